// Round 1
// baseline (882.682 us; speedup 1.0000x reference)
//
#include <hip/hip_runtime.h>

// Problem constants (fixed by the reference setup_inputs).
#define VSZ 50000   // vocab
#define ESZ 100     // embedding dim
#define HSZ 64      // hidden
#define GSZ 256     // 4*H (gate width, PyTorch order i,f,g,o)
#define BSZ 256     // batch
#define TSZ 512     // seq len

__device__ __forceinline__ float fast_rcp(float x) { return __builtin_amdgcn_rcpf(x); }
__device__ __forceinline__ float sigmoid_f(float x) { return fast_rcp(1.f + __expf(-x)); }
// tanh via 1 - 2/(e^{2x}+1): saturates cleanly (inf -> 1, 0 -> -1), no NaN.
__device__ __forceinline__ float tanh_f(float x) {
    float e = __expf(2.f * x);
    return 1.f - 2.f * fast_rcp(e + 1.f);
}

// ---------------------------------------------------------------------------
// Kernel A: G[v, g] = sum_e emb[v,e] * w_ih0[g,e] + b_ih0[g] + b_hh0[g]
// [V,256] fp32 table in workspace (51.2 MB). Thread g holds w_ih0 row g in
// 100 VGPRs; emb rows staged through LDS (broadcast reads).
// ---------------------------------------------------------------------------
__global__ __launch_bounds__(256) void build_table(
    const float* __restrict__ emb, const float* __restrict__ w_ih0,
    const float* __restrict__ b_ih0, const float* __restrict__ b_hh0,
    float* __restrict__ Gt)
{
    const int g = threadIdx.x;
    const int row0 = blockIdx.x * 64;

    float w[ESZ];
    #pragma unroll
    for (int e = 0; e < ESZ; e += 4) {
        float4 v = *(const float4*)(w_ih0 + g * ESZ + e);
        w[e] = v.x; w[e + 1] = v.y; w[e + 2] = v.z; w[e + 3] = v.w;
    }
    const float bias = b_ih0[g] + b_hh0[g];

    __shared__ __align__(16) float rows[8 * ESZ];

    for (int r0 = 0; r0 < 64; r0 += 8) {
        __syncthreads();   // previous chunk's reads done before overwrite
        const int base = (row0 + r0) * ESZ;
        if (base + 8 * ESZ <= VSZ * ESZ) {
            const float4* src = (const float4*)(emb + base);
            float4* dst = (float4*)rows;
            for (int i = g; i < 2 * ESZ; i += 256) dst[i] = src[i];
        } else {
            for (int i = g; i < 8 * ESZ; i += 256)
                rows[i] = (base + i < VSZ * ESZ) ? emb[base + i] : 0.f;
        }
        __syncthreads();
        #pragma unroll 1
        for (int r = 0; r < 8; ++r) {
            const int rr = row0 + r0 + r;
            if (rr >= VSZ) break;
            float a0 = bias, a1 = 0.f, a2 = 0.f, a3 = 0.f;
            #pragma unroll
            for (int e = 0; e < ESZ; e += 4) {
                a0 += rows[r * ESZ + e    ] * w[e    ];
                a1 += rows[r * ESZ + e + 1] * w[e + 1];
                a2 += rows[r * ESZ + e + 2] * w[e + 2];
                a3 += rows[r * ESZ + e + 3] * w[e + 3];
            }
            Gt[(size_t)rr * GSZ + g] = (a0 + a1) + (a2 + a3);
        }
    }
}

// ---------------------------------------------------------------------------
// Kernel B: fused 2-layer LSTM recurrence + FC head.
// One block per batch row (256 blocks -> 1/CU). Thread g owns gate-row g for
// all three recurrent matmuls (weights in 192 VGPRs). h/c state in LDS.
// Custom lgkm-only barrier keeps the next-step G-row prefetch in flight.
// ---------------------------------------------------------------------------
__device__ __forceinline__ void sync_lds() {
    // LDS producer/consumer ordering only; deliberately does NOT drain vmcnt
    // so the G-row prefetch survives the barrier. No global stores in loop.
    asm volatile("s_waitcnt lgkmcnt(0)\n\ts_barrier" ::: "memory");
}

__global__ __launch_bounds__(256, 1) void lstm_fused(
    const int* __restrict__ x, const float* __restrict__ Gt,
    const float* __restrict__ w_hh0,
    const float* __restrict__ w_ih1, const float* __restrict__ w_hh1,
    const float* __restrict__ b_ih1, const float* __restrict__ b_hh1,
    const float* __restrict__ fc_w, const float* __restrict__ fc_b,
    float* __restrict__ out)
{
    const int g = threadIdx.x;      // gate-unit 0..255
    const int b = blockIdx.x;       // batch row
    const int l = g & 63;           // hidden unit this thread updates
    const int gateType = g >> 6;    // 0:i 1:f 2:g 3:o

    __shared__ __align__(16) float h0s[HSZ];
    __shared__ __align__(16) float h1s[HSZ];
    __shared__ __align__(16) float gates[GSZ];
    __shared__ int xtok[TSZ];

    // Recurrent weights -> registers (rows are 256B, 16B-aligned).
    float4 whh0[16], wih1[16], whh1[16];
    #pragma unroll
    for (int k = 0; k < 16; ++k) {
        whh0[k] = *(const float4*)(w_hh0 + g * HSZ + 4 * k);
        wih1[k] = *(const float4*)(w_ih1 + g * HSZ + 4 * k);
        whh1[k] = *(const float4*)(w_hh1 + g * HSZ + 4 * k);
    }
    const float bias1 = b_ih1[g] + b_hh1[g];

    for (int i = g; i < TSZ; i += 256) xtok[i] = x[b * TSZ + i];
    if (g < HSZ) { h0s[g] = 0.f; h1s[g] = 0.f; }
    float c0 = 0.f, c1 = 0.f;
    __syncthreads();

    const float4* h0v4 = (const float4*)h0s;
    const float4* h1v4 = (const float4*)h1s;

    float xg_cur = Gt[(size_t)xtok[0] * GSZ + g];

    for (int t = 0; t < TSZ; ++t) {
        // Prefetch next step's gate-row (coalesced 1KB; ~1 full iter ahead).
        float xg_nxt = 0.f;
        if (t + 1 < TSZ) xg_nxt = Gt[(size_t)xtok[t + 1] * GSZ + g];

        // ---- layer 0 gate pre-activation: xg + w_hh0[g,:] . h0 ----
        float a0 = xg_cur, a1 = 0.f, a2 = 0.f, a3 = 0.f;
        #pragma unroll
        for (int k = 0; k < 16; ++k) {
            float4 hv = h0v4[k];                 // uniform addr -> broadcast
            a0 += whh0[k].x * hv.x; a1 += whh0[k].y * hv.y;
            a2 += whh0[k].z * hv.z; a3 += whh0[k].w * hv.w;
        }
        float pre0 = (a0 + a1) + (a2 + a3);
        float act0 = (gateType == 2) ? tanh_f(pre0) : sigmoid_f(pre0);
        gates[g] = act0;
        sync_lds();

        {   // c/h update, replicated in all 4 waves (identical inputs).
            float gi = gates[l], gf = gates[64 + l];
            float gg = gates[128 + l], go = gates[192 + l];
            c0 = gf * c0 + gi * gg;
            float h0n = go * tanh_f(c0);
            if (g < HSZ) h0s[g] = h0n;           // wave 0 publishes
        }
        sync_lds();

        // ---- layer 1: bias1 + w_ih1[g,:] . h0_new + w_hh1[g,:] . h1 ----
        float b0 = bias1, b1 = 0.f, b2 = 0.f, b3 = 0.f;
        #pragma unroll
        for (int k = 0; k < 16; ++k) {
            float4 h0n = h0v4[k];
            float4 h1v = h1v4[k];
            b0 += wih1[k].x * h0n.x + whh1[k].x * h1v.x;
            b1 += wih1[k].y * h0n.y + whh1[k].y * h1v.y;
            b2 += wih1[k].z * h0n.z + whh1[k].z * h1v.z;
            b3 += wih1[k].w * h0n.w + whh1[k].w * h1v.w;
        }
        float pre1 = (b0 + b1) + (b2 + b3);
        float act1 = (gateType == 2) ? tanh_f(pre1) : sigmoid_f(pre1);
        gates[g] = act1;                         // safe: old reads pre-sync#2
        sync_lds();

        {
            float gi = gates[l], gf = gates[64 + l];
            float gg = gates[128 + l], go = gates[192 + l];
            c1 = gf * c1 + gi * gg;
            float h1n = go * tanh_f(c1);
            if (g < HSZ) h1s[g] = h1n;
        }
        sync_lds();

        xg_cur = xg_nxt;
    }

    // FC head: out[b] = sigmoid(relu(h1s) . fc_w + fc_b), wave 0 only.
    if (g < HSZ) {
        float v = fmaxf(h1s[g], 0.f) * fc_w[g];
        #pragma unroll
        for (int off = 32; off > 0; off >>= 1) v += __shfl_down(v, off, 64);
        if (g == 0) out[b] = sigmoid_f(v + fc_b[0]);
    }
}

extern "C" void kernel_launch(void* const* d_in, const int* in_sizes, int n_in,
                              void* d_out, int out_size, void* d_ws, size_t ws_size,
                              hipStream_t stream) {
    const int*   x     = (const int*)  d_in[0];
    const float* emb   = (const float*)d_in[1];
    const float* w_ih0 = (const float*)d_in[2];
    const float* w_hh0 = (const float*)d_in[3];
    // b_ih0 = d_in[4], b_hh0 = d_in[5] (folded into the table)
    const float* b_ih0 = (const float*)d_in[4];
    const float* b_hh0 = (const float*)d_in[5];
    const float* w_ih1 = (const float*)d_in[6];
    const float* w_hh1 = (const float*)d_in[7];
    const float* b_ih1 = (const float*)d_in[8];
    const float* b_hh1 = (const float*)d_in[9];
    const float* fc_w  = (const float*)d_in[10];
    const float* fc_b  = (const float*)d_in[11];
    float* out = (float*)d_out;

    // Workspace: G table [V, 4H] fp32 = 51.2 MB.
    float* Gt = (float*)d_ws;

    build_table<<<dim3((VSZ + 63) / 64), dim3(256), 0, stream>>>(
        emb, w_ih0, b_ih0, b_hh0, Gt);
    lstm_fused<<<dim3(BSZ), dim3(256), 0, stream>>>(
        x, Gt, w_hh0, w_ih1, w_hh1, b_ih1, b_hh1, fc_w, fc_b, out);
}

// Round 2
// 818.518 us; speedup vs baseline: 1.0784x; 1.0784x over previous
//
#include <hip/hip_runtime.h>

// Problem constants (fixed by the reference setup_inputs).
#define VSZ 50000   // vocab
#define ESZ 100     // embedding dim
#define HSZ 64      // hidden
#define GSZ 256     // 4*H (gate width, PyTorch order i,f,g,o)
#define BSZ 256     // batch
#define TSZ 512     // seq len

__device__ __forceinline__ float fast_rcp(float x) { return __builtin_amdgcn_rcpf(x); }
__device__ __forceinline__ float sigmoid_f(float x) { return fast_rcp(1.f + __expf(-x)); }
// tanh via 1 - 2/(e^{2x}+1): saturates cleanly (inf -> 1, 0 -> -1), no NaN.
__device__ __forceinline__ float tanh_f(float x) {
    float e = __expf(2.f * x);
    return 1.f - 2.f * fast_rcp(e + 1.f);
}

// ---------------------------------------------------------------------------
// Kernel A: G[v, g] = sum_e emb[v,e] * w_ih0[g,e] + b_ih0[g] + b_hh0[g]
// No LDS: emb-row elements are wave-uniform -> force SGPR via readfirstlane
// so they come in on the SMEM pipe (s_load), w_ih0 row stays in VGPRs.
// ---------------------------------------------------------------------------
__global__ __launch_bounds__(256) void build_table(
    const float* __restrict__ emb, const float* __restrict__ w_ih0,
    const float* __restrict__ b_ih0, const float* __restrict__ b_hh0,
    float* __restrict__ Gt)
{
    const int g = threadIdx.x;
    const int row0 = blockIdx.x * 32;

    float w[ESZ];
    #pragma unroll
    for (int e = 0; e < ESZ; e += 4) {
        float4 v = *(const float4*)(w_ih0 + g * ESZ + e);
        w[e] = v.x; w[e + 1] = v.y; w[e + 2] = v.z; w[e + 3] = v.w;
    }
    const float bias = b_ih0[g] + b_hh0[g];

    #pragma unroll 1
    for (int r = row0; r < row0 + 32 && r < VSZ; r += 2) {
        // Uniform (scalar) base offset -> s_load path for emb elements.
        const int off0 = __builtin_amdgcn_readfirstlane(r * ESZ);
        const float* e0 = emb + off0;
        const float* e1 = e0 + ESZ;   // VSZ even, pairs never straddle the end
        float a0 = bias, a1 = 0.f, a2 = 0.f, a3 = 0.f;
        float b0 = bias, b1 = 0.f, b2 = 0.f, b3 = 0.f;
        #pragma unroll
        for (int e = 0; e < ESZ; e += 4) {
            a0 += e0[e    ] * w[e    ]; a1 += e0[e + 1] * w[e + 1];
            a2 += e0[e + 2] * w[e + 2]; a3 += e0[e + 3] * w[e + 3];
            b0 += e1[e    ] * w[e    ]; b1 += e1[e + 1] * w[e + 1];
            b2 += e1[e + 2] * w[e + 2]; b3 += e1[e + 3] * w[e + 3];
        }
        Gt[(size_t)r       * GSZ + g] = (a0 + a1) + (a2 + a3);
        Gt[(size_t)(r + 1) * GSZ + g] = (b0 + b1) + (b2 + b3);
    }
}

// ---------------------------------------------------------------------------
// Kernel B: fused 2-layer LSTM recurrence + FC head.
// One block (512 threads) per batch row. Thread (g = tid>>1, hf = tid&1)
// owns HALF of gate-row g for all three recurrent matmuls: 96 weight floats
// per thread, pinned in VGPRs via empty-asm keep-alives (blocks remat).
// Halves combine with one shfl_xor(1). h/c state + gates in 3.6 KB LDS.
// Custom lgkm-only barrier keeps the next-step G-row prefetch in flight.
// ---------------------------------------------------------------------------
__device__ __forceinline__ void sync_lds() {
    // LDS producer/consumer ordering only; deliberately does NOT drain vmcnt
    // so the G-row prefetch survives the barrier. No global stores in loop.
    asm volatile("s_waitcnt lgkmcnt(0)\n\ts_barrier" ::: "memory");
}

__global__ __launch_bounds__(512, 2) void lstm_fused(
    const int* __restrict__ x, const float* __restrict__ Gt,
    const float* __restrict__ w_hh0,
    const float* __restrict__ w_ih1, const float* __restrict__ w_hh1,
    const float* __restrict__ b_ih1, const float* __restrict__ b_hh1,
    const float* __restrict__ fc_w, const float* __restrict__ fc_b,
    float* __restrict__ out)
{
    const int tid = threadIdx.x;
    const int b   = blockIdx.x;     // batch row
    const int g   = tid >> 1;       // gate-unit 0..255
    const int hf  = tid & 1;        // which half of the dot product
    const int l   = g & 63;         // hidden unit this thread updates
    const int gateType = g >> 6;    // 0:i 1:f 2:g 3:o

    __shared__ __align__(16) float h0s[HSZ];
    __shared__ __align__(16) float h1s[HSZ];
    __shared__ __align__(16) float gates[GSZ];
    __shared__ int xtok[TSZ];

    // Half-rows of the recurrent weights -> 96 VGPRs/thread.
    float4 whh0[8], wih1[8], whh1[8];
    const int wbase = g * HSZ + hf * 32;
    #pragma unroll
    for (int k = 0; k < 8; ++k) {
        whh0[k] = *(const float4*)(w_hh0 + wbase + 4 * k);
        wih1[k] = *(const float4*)(w_ih1 + wbase + 4 * k);
        whh1[k] = *(const float4*)(w_hh1 + wbase + 4 * k);
    }
    // Keep-alive: value becomes an asm output -> compiler cannot re-load it
    // from global memory each iteration (the round-1 failure mode).
    #pragma unroll
    for (int k = 0; k < 8; ++k) {
        asm volatile("" : "+v"(whh0[k].x), "+v"(whh0[k].y), "+v"(whh0[k].z), "+v"(whh0[k].w));
        asm volatile("" : "+v"(wih1[k].x), "+v"(wih1[k].y), "+v"(wih1[k].z), "+v"(wih1[k].w));
        asm volatile("" : "+v"(whh1[k].x), "+v"(whh1[k].y), "+v"(whh1[k].z), "+v"(whh1[k].w));
    }
    const float bias1 = (hf == 0) ? (b_ih1[g] + b_hh1[g]) : 0.f;

    xtok[tid] = x[b * TSZ + tid];                 // 512 threads == TSZ
    if (tid < HSZ) { h0s[tid] = 0.f; h1s[tid] = 0.f; }
    float c0 = 0.f, c1 = 0.f;
    __syncthreads();

    const float4* h0v4 = (const float4*)h0s;
    const float4* h1v4 = (const float4*)h1s;

    float xg_cur = (hf == 0) ? Gt[(size_t)xtok[0] * GSZ + g] : 0.f;

    #pragma unroll 1
    for (int t = 0; t < TSZ; ++t) {
        // Prefetch next step's gate-row half-lane set (~1 full iter ahead).
        float xg_nxt = 0.f;
        if (hf == 0 && t + 1 < TSZ) xg_nxt = Gt[(size_t)xtok[t + 1] * GSZ + g];

        // ---- layer 0: xg + w_hh0[g, hf*32 .. +32) . h0[hf*32 ..] ----
        float a0 = xg_cur, a1 = 0.f, a2 = 0.f, a3 = 0.f;
        #pragma unroll
        for (int k = 0; k < 8; ++k) {
            float4 hv = h0v4[hf * 8 + k];        // 2-way broadcast (free)
            a0 += whh0[k].x * hv.x; a1 += whh0[k].y * hv.y;
            a2 += whh0[k].z * hv.z; a3 += whh0[k].w * hv.w;
        }
        float p = (a0 + a1) + (a2 + a3);
        p += __shfl_xor(p, 1, 64);               // combine halves
        float act0 = (gateType == 2) ? tanh_f(p) : sigmoid_f(p);
        if (hf == 0) gates[g] = act0;
        sync_lds();

        {   // c/h update, replicated (8 threads per unit, identical inputs).
            float gi = gates[l], gf = gates[64 + l];
            float gg = gates[128 + l], go = gates[192 + l];
            c0 = gf * c0 + gi * gg;
            float h0n = go * tanh_f(c0);
            if ((tid & 1) == 0 && tid < 128) h0s[tid >> 1] = h0n;
        }
        sync_lds();

        // ---- layer 1: bias1 + w_ih1[g,:] . h0_new + w_hh1[g,:] . h1 ----
        float q0 = bias1, q1 = 0.f, q2 = 0.f, q3 = 0.f;
        #pragma unroll
        for (int k = 0; k < 8; ++k) {
            float4 hv = h0v4[hf * 8 + k];
            q0 += wih1[k].x * hv.x; q1 += wih1[k].y * hv.y;
            q2 += wih1[k].z * hv.z; q3 += wih1[k].w * hv.w;
        }
        #pragma unroll
        for (int k = 0; k < 8; ++k) {
            float4 hv = h1v4[hf * 8 + k];
            q0 += whh1[k].x * hv.x; q1 += whh1[k].y * hv.y;
            q2 += whh1[k].z * hv.z; q3 += whh1[k].w * hv.w;
        }
        float q = (q0 + q1) + (q2 + q3);
        q += __shfl_xor(q, 1, 64);
        float act1 = (gateType == 2) ? tanh_f(q) : sigmoid_f(q);
        if (hf == 0) gates[g] = act1;            // safe: old reads pre-sync#2
        sync_lds();

        {
            float gi = gates[l], gf = gates[64 + l];
            float gg = gates[128 + l], go = gates[192 + l];
            c1 = gf * c1 + gi * gg;
            float h1n = go * tanh_f(c1);
            if ((tid & 1) == 0 && tid < 128) h1s[tid >> 1] = h1n;
        }
        sync_lds();

        xg_cur = xg_nxt;
    }

    // FC head: out[b] = sigmoid(relu(h1s) . fc_w + fc_b), first wave only.
    if (tid < HSZ) {
        float v = fmaxf(h1s[tid], 0.f) * fc_w[tid];
        #pragma unroll
        for (int off = 32; off > 0; off >>= 1) v += __shfl_down(v, off, 64);
        if (tid == 0) out[b] = sigmoid_f(v + fc_b[0]);
    }
}

extern "C" void kernel_launch(void* const* d_in, const int* in_sizes, int n_in,
                              void* d_out, int out_size, void* d_ws, size_t ws_size,
                              hipStream_t stream) {
    const int*   x     = (const int*)  d_in[0];
    const float* emb   = (const float*)d_in[1];
    const float* w_ih0 = (const float*)d_in[2];
    const float* w_hh0 = (const float*)d_in[3];
    const float* b_ih0 = (const float*)d_in[4];
    const float* b_hh0 = (const float*)d_in[5];
    const float* w_ih1 = (const float*)d_in[6];
    const float* w_hh1 = (const float*)d_in[7];
    const float* b_ih1 = (const float*)d_in[8];
    const float* b_hh1 = (const float*)d_in[9];
    const float* fc_w  = (const float*)d_in[10];
    const float* fc_b  = (const float*)d_in[11];
    float* out = (float*)d_out;

    // Workspace: G table [V, 4H] fp32 = 51.2 MB.
    float* Gt = (float*)d_ws;

    build_table<<<dim3((VSZ + 31) / 32), dim3(256), 0, stream>>>(
        emb, w_ih0, b_ih0, b_hh0, Gt);
    lstm_fused<<<dim3(BSZ), dim3(512), 0, stream>>>(
        x, Gt, w_hh0, w_ih1, w_hh1, b_ih1, b_hh1, fc_w, fc_b, out);
}

// Round 3
// 568.430 us; speedup vs baseline: 1.5528x; 1.4400x over previous
//
#include <hip/hip_runtime.h>

// Problem constants (fixed by the reference setup_inputs).
#define VSZ 50000   // vocab
#define ESZ 100     // embedding dim
#define HSZ 64      // hidden
#define GSZ 256     // 4*H (gate width, PyTorch order i,f,g,o)
#define BSZ 256     // batch
#define TSZ 512     // seq len

__device__ __forceinline__ float fast_rcp(float x) { return __builtin_amdgcn_rcpf(x); }
__device__ __forceinline__ float sigmoid_f(float x) { return fast_rcp(1.f + __expf(-x)); }
// tanh via 1 - 2/(e^{2x}+1): saturates cleanly (inf -> 1, 0 -> -1), no NaN.
__device__ __forceinline__ float tanh_f(float x) {
    float e = __expf(2.f * x);
    return 1.f - 2.f * fast_rcp(e + 1.f);
}

// ---------------------------------------------------------------------------
// Kernel A: G[v, col] = sum_e emb[v,e] * w_ih0[row,e] + b_ih0[row] + b_hh0[row]
// stored PERMUTED: col = 4*(row%64) + row/64, so the recurrent kernel's
// quad layout (unit q, gates g=0..3 at cols 4q+g) reads one coalesced float4.
// ---------------------------------------------------------------------------
__global__ __launch_bounds__(256) void build_table(
    const float* __restrict__ emb, const float* __restrict__ w_ih0,
    const float* __restrict__ b_ih0, const float* __restrict__ b_hh0,
    float* __restrict__ Gt)
{
    const int g = threadIdx.x;            // PyTorch gate-row index 0..255
    const int row0 = blockIdx.x * 32;
    const int col = ((g & 63) << 2) + (g >> 6);   // permuted column

    float w[ESZ];
    #pragma unroll
    for (int e = 0; e < ESZ; e += 4) {
        float4 v = *(const float4*)(w_ih0 + g * ESZ + e);
        w[e] = v.x; w[e + 1] = v.y; w[e + 2] = v.z; w[e + 3] = v.w;
    }
    const float bias = b_ih0[g] + b_hh0[g];

    #pragma unroll 1
    for (int r = row0; r < row0 + 32 && r < VSZ; r += 2) {
        const int off0 = __builtin_amdgcn_readfirstlane(r * ESZ);
        const float* e0 = emb + off0;
        const float* e1 = e0 + ESZ;   // VSZ even, pairs never straddle the end
        float a0 = bias, a1 = 0.f, a2 = 0.f, a3 = 0.f;
        float b0 = bias, b1 = 0.f, b2 = 0.f, b3 = 0.f;
        #pragma unroll
        for (int e = 0; e < ESZ; e += 4) {
            a0 += e0[e    ] * w[e    ]; a1 += e0[e + 1] * w[e + 1];
            a2 += e0[e + 2] * w[e + 2]; a3 += e0[e + 3] * w[e + 3];
            b0 += e1[e    ] * w[e    ]; b1 += e1[e + 1] * w[e + 1];
            b2 += e1[e + 2] * w[e + 2]; b3 += e1[e + 3] * w[e + 3];
        }
        Gt[(size_t)r       * GSZ + col] = (a0 + a1) + (a2 + a3);
        Gt[(size_t)(r + 1) * GSZ + col] = (b0 + b1) + (b2 + b3);
    }
}

// ---------------------------------------------------------------------------
// Kernel B: fused 2-layer LSTM + FC head, 1 block (512 thr) per batch row.
//
// Decomposition: local thread lt in [0,256): quad q = lt>>2 (hidden unit),
// j = lt&3 (k-slice of 16 h-values). Thread holds k-slice j of the 4 gate
// rows {q, 64+q, 128+q, 192+q} as 16 (group A) / 32 (group B) NAMED float4
// registers (no arrays -> cannot be demoted to scratch; keep-alive asm each
// iteration -> cannot be re-loaded; this was the r1/r2 failure).
// Partial dots -> 4-lane allreduce (shfl_xor 1,2) -> every lane has all 4
// gate pre-acts for unit q -> activations + c-update replicated, lane j==0
// publishes h.
//
// Pipeline: waves 0-3 (A) run layer 0 at step k while waves 4-7 (B) run
// layer 1 at step k-1 (both only need h0(k-1)); ONE lgkm-only barrier per
// step, so the Gt gather prefetch stays in flight across it.
// ---------------------------------------------------------------------------
__device__ __forceinline__ void sync_lds() {
    asm volatile("s_waitcnt lgkmcnt(0)\n\ts_barrier" ::: "memory");
}

#define LD4(ptr, off) (*(const float4*)((ptr) + (off)))
#define K4(v) asm volatile("" : "+v"(v.x), "+v"(v.y), "+v"(v.z), "+v"(v.w))
#define KEEPALL \
  K4(W00);K4(W01);K4(W02);K4(W03);K4(W10);K4(W11);K4(W12);K4(W13); \
  K4(W20);K4(W21);K4(W22);K4(W23);K4(W30);K4(W31);K4(W32);K4(W33); \
  K4(U00);K4(U01);K4(U02);K4(U03);K4(U10);K4(U11);K4(U12);K4(U13); \
  K4(U20);K4(U21);K4(U22);K4(U23);K4(U30);K4(U31);K4(U32);K4(U33)
#define DOTACC(p, W, h) p += W.x*h.x; p += W.y*h.y; p += W.z*h.z; p += W.w*h.w

__global__ __launch_bounds__(512, 2) void lstm_fused(
    const int* __restrict__ x, const float* __restrict__ Gt,
    const float* __restrict__ w_hh0,
    const float* __restrict__ w_ih1, const float* __restrict__ w_hh1,
    const float* __restrict__ b_ih1, const float* __restrict__ b_hh1,
    const float* __restrict__ fc_w, const float* __restrict__ fc_b,
    float* __restrict__ out)
{
    const int tid = threadIdx.x;
    const int b   = blockIdx.x;
    const bool isA = tid < 256;     // waves 0-3: layer 0; waves 4-7: layer 1
    const int lt  = tid & 255;
    const int q   = lt >> 2;        // hidden unit
    const int j   = lt & 3;         // k-slice (h[16j .. 16j+16))

    __shared__ __align__(16) float h0b[2][HSZ];
    __shared__ __align__(16) float h1b[2][HSZ];
    __shared__ int xtok[TSZ];

    // Weight slices. Row of gate g = g*64+q; addr = row*64 + 16j + 4m
    //  -> base + g*4096 + 4m with base = q*64 + 16j.
    const float* bW = (isA ? w_hh0 : w_ih1) + (q * HSZ + 16 * j);
    const float* bU = w_hh1 + (q * HSZ + 16 * j);   // loaded by all, used by B

    float4 W00=LD4(bW,0),     W01=LD4(bW,4),     W02=LD4(bW,8),     W03=LD4(bW,12);
    float4 W10=LD4(bW,4096),  W11=LD4(bW,4100),  W12=LD4(bW,4104),  W13=LD4(bW,4108);
    float4 W20=LD4(bW,8192),  W21=LD4(bW,8196),  W22=LD4(bW,8200),  W23=LD4(bW,8204);
    float4 W30=LD4(bW,12288), W31=LD4(bW,12292), W32=LD4(bW,12296), W33=LD4(bW,12300);
    float4 U00=LD4(bU,0),     U01=LD4(bU,4),     U02=LD4(bU,8),     U03=LD4(bU,12);
    float4 U10=LD4(bU,4096),  U11=LD4(bU,4100),  U12=LD4(bU,4104),  U13=LD4(bU,4108);
    float4 U20=LD4(bU,8192),  U21=LD4(bU,8196),  U22=LD4(bU,8200),  U23=LD4(bU,8204);
    float4 U30=LD4(bU,12288), U31=LD4(bU,12292), U32=LD4(bU,12296), U33=LD4(bU,12300);

    float bi0 = 0.f, bi1 = 0.f, bi2 = 0.f, bi3 = 0.f;
    if (!isA) {
        bi0 = b_ih1[q]       + b_hh1[q];
        bi1 = b_ih1[64 + q]  + b_hh1[64 + q];
        bi2 = b_ih1[128 + q] + b_hh1[128 + q];
        bi3 = b_ih1[192 + q] + b_hh1[192 + q];
    }

    if (tid < 128)      ((float*)h0b)[tid] = 0.f;
    else if (tid < 256) ((float*)h1b)[tid - 128] = 0.f;
    xtok[tid] = x[b * TSZ + tid];                 // 512 threads == TSZ
    __syncthreads();

    // A: xg(k=0) pre-gather (cols 4q..4q+3 of the permuted table).
    float4 xg = LD4(Gt, (size_t)xtok[0] * GSZ + 4 * q);
    float c = 0.f;                                // c0 (A) / c1 (B)

    #pragma unroll 1
    for (int k = 0; k <= TSZ; ++k) {
        KEEPALL;   // 0-instruction register pins: no remat, no scratch

        const int rb = (k ^ 1) & 1;               // (k-1) & 1
        // --- common: W-part dot against h0(k-1) slice ---
        const float4* h0v = (const float4*)h0b[rb];
        float4 ha = h0v[j*4+0], hb = h0v[j*4+1], hc = h0v[j*4+2], hd = h0v[j*4+3];
        float p0 = 0.f, p1 = 0.f, p2 = 0.f, p3 = 0.f;
        DOTACC(p0,W00,ha); DOTACC(p0,W01,hb); DOTACC(p0,W02,hc); DOTACC(p0,W03,hd);
        DOTACC(p1,W10,ha); DOTACC(p1,W11,hb); DOTACC(p1,W12,hc); DOTACC(p1,W13,hd);
        DOTACC(p2,W20,ha); DOTACC(p2,W21,hb); DOTACC(p2,W22,hc); DOTACC(p2,W23,hd);
        DOTACC(p3,W30,ha); DOTACC(p3,W31,hb); DOTACC(p3,W32,hc); DOTACC(p3,W33,hd);

        if (!isA && k >= 1) {                     // + U-part dot against h1(k-2)
            const float4* h1v = (const float4*)h1b[k & 1];
            float4 ea = h1v[j*4+0], eb = h1v[j*4+1], ec = h1v[j*4+2], ed = h1v[j*4+3];
            DOTACC(p0,U00,ea); DOTACC(p0,U01,eb); DOTACC(p0,U02,ec); DOTACC(p0,U03,ed);
            DOTACC(p1,U10,ea); DOTACC(p1,U11,eb); DOTACC(p1,U12,ec); DOTACC(p1,U13,ed);
            DOTACC(p2,U20,ea); DOTACC(p2,U21,eb); DOTACC(p2,U22,ec); DOTACC(p2,U23,ed);
            DOTACC(p3,U30,ea); DOTACC(p3,U31,eb); DOTACC(p3,U32,ec); DOTACC(p3,U33,ed);
        }

        // --- 4-lane allreduce: every lane gets all 4 gate dots of unit q ---
        p0 += __shfl_xor(p0, 1, 64); p0 += __shfl_xor(p0, 2, 64);
        p1 += __shfl_xor(p1, 1, 64); p1 += __shfl_xor(p1, 2, 64);
        p2 += __shfl_xor(p2, 1, 64); p2 += __shfl_xor(p2, 2, 64);
        p3 += __shfl_xor(p3, 1, 64); p3 += __shfl_xor(p3, 2, 64);

        if (isA) {
            if (k < TSZ) {                        // layer-0 step k
                float4 xg_n;
                const bool pf = (k + 1 < TSZ);
                if (pf) xg_n = LD4(Gt, (size_t)xtok[k + 1] * GSZ + 4 * q);
                float ig = sigmoid_f(p0 + xg.x);
                float fg = sigmoid_f(p1 + xg.y);
                float gg = tanh_f   (p2 + xg.z);
                float og = sigmoid_f(p3 + xg.w);
                c = fg * c + ig * gg;
                float hn = og * tanh_f(c);
                if (j == 0) h0b[k & 1][q] = hn;
                if (pf) xg = xg_n;
            }
        } else {
            if (k >= 1) {                         // layer-1 step k-1
                float ig = sigmoid_f(p0 + bi0);
                float fg = sigmoid_f(p1 + bi1);
                float gg = tanh_f   (p2 + bi2);
                float og = sigmoid_f(p3 + bi3);
                c = fg * c + ig * gg;
                float hn = og * tanh_f(c);
                if (j == 0) h1b[(k ^ 1) & 1][q] = hn;
            }
        }
        sync_lds();   // lgkm-only: Gt prefetch survives the barrier
    }

    // FC head on h1(T-1) = h1b[1] (wave 0 only).
    if (tid < HSZ) {
        float v = fmaxf(h1b[1][tid], 0.f) * fc_w[tid];
        #pragma unroll
        for (int off = 32; off > 0; off >>= 1) v += __shfl_down(v, off, 64);
        if (tid == 0) out[b] = sigmoid_f(v + fc_b[0]);
    }
}

extern "C" void kernel_launch(void* const* d_in, const int* in_sizes, int n_in,
                              void* d_out, int out_size, void* d_ws, size_t ws_size,
                              hipStream_t stream) {
    const int*   x     = (const int*)  d_in[0];
    const float* emb   = (const float*)d_in[1];
    const float* w_ih0 = (const float*)d_in[2];
    const float* w_hh0 = (const float*)d_in[3];
    const float* b_ih0 = (const float*)d_in[4];
    const float* b_hh0 = (const float*)d_in[5];
    const float* w_ih1 = (const float*)d_in[6];
    const float* w_hh1 = (const float*)d_in[7];
    const float* b_ih1 = (const float*)d_in[8];
    const float* b_hh1 = (const float*)d_in[9];
    const float* fc_w  = (const float*)d_in[10];
    const float* fc_b  = (const float*)d_in[11];
    float* out = (float*)d_out;

    // Workspace: permuted G table [V, 4H] fp32 = 51.2 MB.
    float* Gt = (float*)d_ws;

    build_table<<<dim3((VSZ + 31) / 32), dim3(256), 0, stream>>>(
        emb, w_ih0, b_ih0, b_hh0, Gt);
    lstm_fused<<<dim3(BSZ), dim3(512), 0, stream>>>(
        x, Gt, w_hh0, w_ih1, w_hh1, b_ih1, b_hh1, fc_w, fc_b, out);
}